// Round 12
// baseline (43.670 us; speedup 1.0000x reference)
//
#include <hip/hip_runtime.h>

typedef __attribute__((ext_vector_type(8))) short   bf16x8;
typedef __attribute__((ext_vector_type(4))) float   f32x4;
typedef __attribute__((ext_vector_type(4))) unsigned int u32x4;

#define HT    8        // output rows per block
#define WT    32       // output w columns per block
#define WSPAN 34       // staged w columns: WT + 2 halo
#define NR    10       // staged rows: HT + 2

__device__ __forceinline__ unsigned short f2bf(float f) {
    union { float f; unsigned u; } v; v.f = f;
    unsigned u = v.u;
    u += 0x7FFFu + ((u >> 16) & 1u);   // RNE
    return (unsigned short)(u >> 16);
}

// Fused conv, 32-wide tiles, 4-deep staging pipeline: stage the 10x34x32
// input tile to LDS (bf16, zero-filled OOB) with NO barriers and 4 rows of
// loads in flight, ONE __syncthreads(), then barrier-free MFMA compute.
__global__ __launch_bounds__(256, 4)
void conv3x3_fused(const float* __restrict__ x, const float* __restrict__ wk,
                   float* __restrict__ out) {
    const int hb = blockIdx.x, wq4 = blockIdx.y, n = blockIdx.z;
    const int H0 = hb * HT, W0 = wq4 * WT;
    const int tid  = threadIdx.x;
    const int lane = tid & 63, wid = tid >> 6;
    const int lq = lane >> 4, lr = lane & 15;

    __shared__ u32x4 lds[NR * WSPAN * 4];   // 21,760 B

    // ---- staging task: 136 tasks/row (34 wq x 4 c-octets), threads 0..135 ----
    const bool act = (tid < 136);
    const int cb = (tid < 128) ? (tid >> 5) : ((tid - 128) >> 1);
    const int wq = (tid < 128) ? (tid & 31) : (32 + ((tid - 128) & 1));

    auto issue_loads = [&](int rg, float (&dst)[8]) {
        const int wg = W0 - 1 + wq;
        const bool ok = act && ((unsigned)rg < 128u) && ((unsigned)wg < 128u);
        const float* p = x + (((n * 32 + cb * 8) * 128 + rg) * 128 + wg);
        #pragma unroll
        for (int j = 0; j < 8; ++j)
            dst[j] = ok ? p[j * 16384] : 0.0f;   // channel stride = H*W
    };
    // swizzle f=(wq>>1)&3: measured conflict-free (R3/R10: SQ_LDS_BANK_CONFLICT=0)
    auto lds_write = [&](int row, const float (&src)[8]) {
        if (!act) return;
        const int f = (wq >> 1) & 3;
        u32x4 pk;
        pk[0] = (unsigned)f2bf(src[0]) | ((unsigned)f2bf(src[1]) << 16);
        pk[1] = (unsigned)f2bf(src[2]) | ((unsigned)f2bf(src[3]) << 16);
        pk[2] = (unsigned)f2bf(src[4]) | ((unsigned)f2bf(src[5]) << 16);
        pk[3] = (unsigned)f2bf(src[6]) | ((unsigned)f2bf(src[7]) << 16);
        lds[(row * WSPAN + wq) * 4 + (cb ^ f)] = pk;
    };
    auto frag_read = [&](int row, int w) -> bf16x8 {
        const int f = (w >> 1) & 3;
        union { u32x4 u; bf16x8 v; } cv;
        cv.u = lds[(row * WSPAN + w) * 4 + (lq ^ f)];
        return cv.v;
    };

    // ---- stage all NR rows, 4-deep register pipeline, zero barriers ----
    float buf[4][8];
    issue_loads(H0 - 1, buf[0]);    // staged row 0
    issue_loads(H0,     buf[1]);    // staged row 1
    issue_loads(H0 + 1, buf[2]);    // staged row 2
    issue_loads(H0 + 2, buf[3]);    // staged row 3

#define STAGE(R)                                                              \
    {                                                                         \
        lds_write((R), buf[(R) & 3]);                                         \
        if ((R) + 4 < NR) issue_loads(H0 + (R) + 3, buf[(R) & 3]);            \
    }
    STAGE(0) STAGE(1) STAGE(2) STAGE(3) STAGE(4)
    STAGE(5) STAGE(6) STAGE(7) STAGE(8) STAGE(9)
#undef STAGE

    // ---- weights -> registers: wave `wid` owns och tile [wid*16, wid*16+16) ----
    // Raw buffer index: ((c*3+ki)*3+kj)*64 + o   (reshape quirk).
    bf16x8 wA[9];
    #pragma unroll
    for (int p = 0; p < 9; ++p) {
        const int ki = p / 3, kj = p % 3;
        union { bf16x8 v; unsigned short s[8]; } u;
        #pragma unroll
        for (int j = 0; j < 8; ++j) {
            const int c = lq * 8 + j;
            u.s[j] = f2bf(wk[((c * 3 + ki) * 3 + kj) * 64 + wid * 16 + lr]);
        }
        wA[p] = u.v;
    }

    __syncthreads();   // the ONLY barrier

    // ---- accumulators: 3-row ring x 2 pixel groups ----
    f32x4 acc[3][2];
    const f32x4 zero = {0.f, 0.f, 0.f, 0.f};
    #pragma unroll
    for (int a = 0; a < 3; ++a)
        #pragma unroll
        for (int pg = 0; pg < 2; ++pg) acc[a][pg] = zero;

    // per-thread output base: o = wid*16 + lq*4 (+j), w = W0 + lr (+pg*16)
    float* obase = out + (((size_t)(n * 64 + wid * 16 + lq * 4) * 128) * 128) + W0 + lr;

    // staged row RHO (zero-filled if OOB) feeds h = H0+RHO-ki; row h completes
    // at RHO = h-H0+2. All indices literal.
#define ROW(RHO)                                                              \
    {                                                                         \
        _Pragma("unroll")                                                     \
        for (int pg = 0; pg < 2; ++pg) {                                      \
            const bf16x8 fb0 = frag_read((RHO), pg * 16 + lr + 0);            \
            const bf16x8 fb1 = frag_read((RHO), pg * 16 + lr + 1);            \
            const bf16x8 fb2 = frag_read((RHO), pg * 16 + lr + 2);            \
            _Pragma("unroll")                                                 \
            for (int ki = 0; ki < 3; ++ki) {                                  \
                if ((RHO) - ki < 0 || (RHO) - ki > HT - 1) continue;          \
                const int a = ((RHO) - ki + 1) % 3;                           \
                acc[a][pg] = __builtin_amdgcn_mfma_f32_16x16x32_bf16(         \
                    wA[ki * 3 + 0], fb0, acc[a][pg], 0, 0, 0);                \
                acc[a][pg] = __builtin_amdgcn_mfma_f32_16x16x32_bf16(         \
                    wA[ki * 3 + 1], fb1, acc[a][pg], 0, 0, 0);                \
                acc[a][pg] = __builtin_amdgcn_mfma_f32_16x16x32_bf16(         \
                    wA[ki * 3 + 2], fb2, acc[a][pg], 0, 0, 0);                \
            }                                                                 \
        }                                                                     \
        if ((RHO) >= 2) {                                                     \
            const int h = H0 + (RHO) - 2;                                     \
            const int a = ((RHO) - 1) % 3;                                    \
            _Pragma("unroll")                                                 \
            for (int pg = 0; pg < 2; ++pg) {                                  \
                _Pragma("unroll")                                             \
                for (int j = 0; j < 4; ++j)                                   \
                    obase[(j * 128 + h) * 128 + pg * 16] = acc[a][pg][j];     \
                acc[a][pg] = zero;                                            \
            }                                                                 \
        }                                                                     \
    }

    ROW(0) ROW(1) ROW(2) ROW(3) ROW(4) ROW(5) ROW(6) ROW(7) ROW(8) ROW(9)
#undef ROW
}

extern "C" void kernel_launch(void* const* d_in, const int* in_sizes, int n_in,
                              void* d_out, int out_size, void* d_ws, size_t ws_size,
                              hipStream_t stream) {
    const float* x  = (const float*)d_in[0];
    const float* wk = (const float*)d_in[1];
    float* out = (float*)d_out;
    dim3 grid(16, 4, 32);   // hb, w-quarter, n  -> 2048 blocks
    dim3 block(256);
    conv3x3_fused<<<grid, block, 0, stream>>>(x, wk, out);
}